// Round 14
// baseline (171.265 us; speedup 1.0000x reference)
//
#include <hip/hip_runtime.h>
#include <hip/hip_bf16.h>
#include <stdint.h>

#define TEMPERATURE 0.07f
#define SC 20.6099312f   // log2(e)/T  (SC*ln2 == 1/T; cancellation used in k_rowfin)

constexpr int NQ = 256;
constexpr int KQ = 8192;
constexpr int D  = 128;
constexpr int N  = NQ + 2 * KQ;   // 16640
constexpr int NSTRIP = 260;       // 64-col strips
constexpr int NCH = 52;           // row-chunks (10 x 32-row tiles each)
constexpr int RBF = N / 256;      // 65 blocks for k_rowfin

typedef float f32x16 __attribute__((ext_vector_type(16)));
typedef int   i32x4  __attribute__((ext_vector_type(4)));
typedef int   i32x8  __attribute__((ext_vector_type(8)));

// ---- workspace layout (bytes) ----
constexpr size_t OFF_F32  = 0;                                     // float feat [NQ][D] (q rows only)
constexpr size_t OFF_8    = OFF_F32  + (size_t)NQ * D * 4;         // fp8 feat (B side) [N][128]
constexpr size_t OFF_8S   = OFF_8    + (size_t)N * D;              // fp8 feat * SC (A side) [N][128]
constexpr size_t OFF_PR   = OFF_8S   + (size_t)N * D;              // part_row [260][N]
constexpr size_t OFF_PC   = OFF_PR   + (size_t)NSTRIP * N * 4;     // part_col [52][N]
constexpr size_t OFF_LP   = OFF_PC   + (size_t)NCH * N * 4;        // label partials [260][2][128]
constexpr size_t OFF_BSUM = OFF_LP   + (size_t)260 * 2 * 128 * 4;  // blocksum [65]

#define MFMA8(a, b, c) __builtin_amdgcn_mfma_scale_f32_32x32x64_f8f6f4( \
    (a), (b), (c), 0, 0, 0, 0x7f7f7f7f, 0, 0x7f7f7f7f)

// ---------------------------------------------------------------------------
// K1: normalize features; emit f32 (q rows only) + two natural-row-major fp8
// copies (unscaled B side, SC-prescaled A side); per-label per-dim partials.
// ---------------------------------------------------------------------------
__global__ __launch_bounds__(256) void k_prep(const float* __restrict__ q,
                                              const float* __restrict__ ba,
                                              const float* __restrict__ nb,
                                              const long long* __restrict__ tgt,
                                              float* __restrict__ ff,
                                              unsigned char* __restrict__ fb8,
                                              unsigned char* __restrict__ fb8s,
                                              float* __restrict__ lp) {
    __shared__ float red[4][2][128];
    int wid = threadIdx.x >> 6, lane = threadIdx.x & 63;
    int rbase = blockIdx.x * 64 + wid * 16;
    float s0x = 0.f, s0y = 0.f, s1x = 0.f, s1y = 0.f;
    for (int i = 0; i < 16; ++i) {
        int r = rbase + i;
        const float* src = (r < NQ) ? (q + (size_t)r * D)
                         : (r < NQ + KQ) ? (ba + (size_t)(r - NQ) * D)
                         : (nb + (size_t)(r - NQ - KQ) * D);
        float2 v = *(const float2*)(src + lane * 2);
        float a = v.x, b = v.y;
        int lab;
        if (r < NQ) {
            float ss = a * a + b * b;
            #pragma unroll
            for (int m = 1; m < 64; m <<= 1) ss += __shfl_xor(ss, m);
            float scale = 1.0f / fmaxf(sqrtf(ss), 1e-12f);
            a *= scale; b *= scale;
            lab = (int)tgt[r];
            *(float2*)(ff + (size_t)r * D + lane * 2) = make_float2(a, b);
        } else {
            lab = (r < NQ + KQ) ? 1 : 0;
        }
        int w8  = __builtin_amdgcn_cvt_pk_fp8_f32(a, b, 0, false);
        int w8s = __builtin_amdgcn_cvt_pk_fp8_f32(a * SC, b * SC, 0, false);
        *(unsigned short*)(fb8  + (size_t)r * D + lane * 2) = (unsigned short)w8;
        *(unsigned short*)(fb8s + (size_t)r * D + lane * 2) = (unsigned short)w8s;
        if (lab) { s1x += a; s1y += b; } else { s0x += a; s0y += b; }
    }
    red[wid][0][lane * 2]     = s0x;
    red[wid][0][lane * 2 + 1] = s0y;
    red[wid][1][lane * 2]     = s1x;
    red[wid][1][lane * 2 + 1] = s1y;
    __syncthreads();
    int lab2 = threadIdx.x >> 7, d = threadIdx.x & 127;
    float s = red[0][lab2][d] + red[1][lab2][d] + red[2][lab2][d] + red[3][lab2][d];
    lp[((size_t)blockIdx.x * 2 + lab2) * 128 + d] = s;
}

// ---------------------------------------------------------------------------
// K3: SYMMETRIC upper-triangle fused MX-fp8 GEMM + exp sums (row AND col).
//   Wave-job: strip J (64 cols, A-frags in regs from fb8s) x chunk ch of
//   <=10 row-tiles (32 rows, 4KB, wave-private LDS dbuf, counted vmcnt(4),
//   NO barriers). Tile (J, nt) computed iff nt <= 2J+1 (upper triangle).
//   Each exp feeds: row path -> part_row[J][row] (in-lane), col path ->
//   colacc regs (fixed cols across tiles) -> LDS transpose-reduce at job end
//   -> part_col[ch][col]. Diagonal tiles (nt >= 2J): row path only.
//   Slot map: all 4 waves of a block share J (balanced tile counts).
// ---------------------------------------------------------------------------
__global__ __launch_bounds__(256, 4) void k_main(const unsigned char* __restrict__ fb8,
                                                 const unsigned char* __restrict__ fb8s,
                                                 float* __restrict__ part_row,
                                                 float* __restrict__ part_col) {
    __shared__ __align__(16) unsigned char lds[4][8192];   // per-wave 8KB (dbuf + reduce scratch)
    const int tid = threadIdx.x;
    const int lane = tid & 63;
    const int wid  = tid >> 6;                 // 0..3
    const int slot = blockIdx.x + 3380 * wid;  // same J for all waves of a block
    const int J  = slot % NSTRIP;              // column strip (64 cols)
    const int ch = slot / NSTRIP;              // row chunk (10 x 32-row tiles)
    const int nt0   = ch * 10;
    const int ntend = min(nt0 + 10, 2 * J + 2);
    if (nt0 >= ntend) return;                  // dead slot (below triangle)
    const int l31 = lane & 31, lhi = lane >> 5;

    unsigned char* myl = &lds[wid][0];

    // A-frags: 64 cols of strip J (scaled side), loaded once. [cc][s]
    i32x8 af[2][2];
    #pragma unroll
    for (int cc = 0; cc < 2; ++cc)
        #pragma unroll
        for (int s = 0; s < 2; ++s)
            af[cc][s] = *(const i32x8*)(fb8s + (size_t)(64 * J + cc * 32 + l31) * D + s * 64 + lhi * 32);

    // staging source offsets (2-rows/256B-line, 16-slot XOR; R7-verified 0-conflict)
    int soff[4];
    #pragma unroll
    for (int i = 0; i < 4; ++i) {
        int flat = i * 64 + lane;                 // 0..255 (16B units of a 4KB tile)
        int line = flat >> 4, sl = flat & 15;
        int pl = sl ^ line;                       // lines 0..15
        soff[i] = (2 * line + (pl >> 3)) * 128 + (pl & 7) * 16;
    }
    // B-read offsets [s][lo/hi]: row n=l31, chunk p = (n&1)*8 + s*4 + lhi*2
    int lofs[2][2];
    #pragma unroll
    for (int s = 0; s < 2; ++s) {
        int line = l31 >> 1;
        int p = ((l31 & 1) << 3) + s * 4 + lhi * 2;
        lofs[s][0] = line * 256 + ((p    ) ^ line) * 16;
        lofs[s][1] = line * 256 + ((p + 1) ^ line) * 16;
    }

#define STAGE(NT, B) { \
    const unsigned char* base_ = fb8 + (size_t)(NT) * 4096; \
    _Pragma("unroll") \
    for (int i_ = 0; i_ < 4; ++i_) \
        __builtin_amdgcn_global_load_lds( \
            (const __attribute__((address_space(1))) unsigned int*)(base_ + soff[i_]), \
            (__attribute__((address_space(3))) unsigned int*)(myl + (B) * 4096 + (i_ * 64 + lane) * 16), \
            16, 0, 0); }

    f32x16 z16, cA, cB;
    #pragma unroll
    for (int e = 0; e < 16; ++e) { z16[e] = 0.f; cA[e] = 0.f; cB[e] = 0.f; }

    STAGE(nt0, 0)

    for (int nt = nt0; nt < ntend; ++nt) {
        int b = (nt - nt0) & 1;
        if (nt + 1 < ntend) {
            STAGE(nt + 1, b ^ 1)
            asm volatile("s_waitcnt vmcnt(4)" ::: "memory");   // tile nt landed
        } else {
            asm volatile("s_waitcnt vmcnt(0)" ::: "memory");
        }
        const unsigned char* buf = myl + b * 4096;

        f32x16 acc0, acc1;
        __builtin_amdgcn_s_setprio(1);
        #pragma unroll
        for (int s = 0; s < 2; ++s) {
            i32x4 lo = *(const i32x4*)(buf + lofs[s][0]);
            i32x4 hi = *(const i32x4*)(buf + lofs[s][1]);
            i32x8 bb = {lo[0], lo[1], lo[2], lo[3], hi[0], hi[1], hi[2], hi[3]};
            acc0 = MFMA8(af[0][s], bb, (s == 0) ? z16 : acc0);
            acc1 = MFMA8(af[1][s], bb, (s == 0) ? z16 : acc1);
        }
        __builtin_amdgcn_s_setprio(0);

        float rowp = 0.f;
        if (nt < 2 * J) {
            // off-diagonal: exp feeds both row and col sums
            #pragma unroll
            for (int g = 0; g < 16; ++g) {
                float e0 = __builtin_amdgcn_exp2f(acc0[g]);
                float e1 = __builtin_amdgcn_exp2f(acc1[g]);
                rowp += e0 + e1;
                cA[g] += e0; cB[g] += e1;
            }
        } else {
            // diagonal tile: row path only (avoids double count)
            #pragma unroll
            for (int g = 0; g < 16; ++g)
                rowp += __builtin_amdgcn_exp2f(acc0[g]) + __builtin_amdgcn_exp2f(acc1[g]);
        }
        rowp += __shfl_xor(rowp, 32);
        if (lane < 32)
            part_row[(size_t)J * N + 32 * nt + l31] = rowp;
    }

    // --- job-end column reduce: colacc -> LDS transpose -> part_col -------
    // store: lane row, 8 x 16B chunks, chunk-XOR by (lane&7)
    #pragma unroll
    for (int j4 = 0; j4 < 4; ++j4) {
        float4 vA = {cA[j4 * 4 + 0], cA[j4 * 4 + 1], cA[j4 * 4 + 2], cA[j4 * 4 + 3]};
        float4 vB = {cB[j4 * 4 + 0], cB[j4 * 4 + 1], cB[j4 * 4 + 2], cB[j4 * 4 + 3]};
        *(float4*)(myl + lane * 128 + ((j4    ) ^ (lane & 7)) * 16) = vA;
        *(float4*)(myl + lane * 128 + ((j4 + 4) ^ (lane & 7)) * 16) = vB;
    }
    asm volatile("s_waitcnt lgkmcnt(0)" ::: "memory");
    // read: lane j owns column 64J + j; m(j): cc=j>>5, reg=(j&3)|(((j>>3)&3)<<2), lhi=(j>>2)&1
    int lhij = (lane >> 2) & 1;
    int slj  = ((lane >> 5) << 4) | (lane & 3) | (((lane >> 3) & 3) << 2);   // cc*16+reg
    float csum = 0.f;
    #pragma unroll 8
    for (int s2 = 0; s2 < 32; ++s2) {
        int srcr = s2 + (lhij << 5);
        int phys = (slj >> 2) ^ (s2 & 7);
        csum += *(const float*)(myl + srcr * 128 + phys * 16 + (slj & 3) * 4);
    }
    part_col[(size_t)ch * N + 64 * J + lane] = csum;
#undef STAGE
}

// ---------------------------------------------------------------------------
// K4: per-row finalize. Redundant lp->S reduction + counts per block, then
// se = sum_J part_row[J][r] (J>=r/64) + sum_ch part_col[ch][r] - exp2(dd);
// lse = log(se_raw) (the 1/T shift cancels: SC*ln2 == 1/T).
// ---------------------------------------------------------------------------
__global__ __launch_bounds__(256) void k_rowfin(const float* __restrict__ part_row,
                                                const float* __restrict__ part_col,
                                                const float* __restrict__ ff,
                                                const float* __restrict__ ba,
                                                const float* __restrict__ nb,
                                                const float* __restrict__ lp,
                                                const long long* __restrict__ tgt,
                                                float* __restrict__ bsum) {
    __shared__ float sS[256];
    __shared__ float red[256];
    __shared__ int scnt[2];
    {   // S reduction (redundant per block; fixed order -> deterministic)
        int lab = threadIdx.x >> 7, d = threadIdx.x & 127;
        float s[4] = {0.f, 0.f, 0.f, 0.f};
        for (int b = 0; b < 260; b += 4) {
            #pragma unroll
            for (int j = 0; j < 4; ++j)
                s[j] += lp[((size_t)(b + j) * 2 + lab) * 128 + d];
        }
        sS[threadIdx.x] = (s[0] + s[1]) + (s[2] + s[3]);
        if (threadIdx.x < 64) {
            int c = 0;
            #pragma unroll
            for (int i = 0; i < 4; ++i) c += (int)tgt[threadIdx.x + 64 * i];
            #pragma unroll
            for (int m = 1; m < 64; m <<= 1) c += __shfl_xor(c, m);
            if (threadIdx.x == 0) { scnt[0] = (NQ - c) + KQ; scnt[1] = c + KQ; }
        }
    }
    __syncthreads();
    int r = blockIdx.x * 256 + threadIdx.x;
    int J0 = r >> 6;
    float se = 0.f;
    for (int Jx = J0; Jx < NSTRIP; ++Jx) se += part_row[(size_t)Jx * N + r];
    int nch = (2 * J0 + 1) / 10 + 1;
    for (int c2 = 0; c2 < nch; ++c2) se += part_col[(size_t)c2 * N + r];
    int lab = (r < NQ) ? (int)tgt[r] : ((r < NQ + KQ) ? 1 : 0);
    const float* fsrc = (r < NQ) ? (ff + (size_t)r * D)
                      : (r < NQ + KQ) ? (ba + (size_t)(r - NQ) * D)
                      : (nb + (size_t)(r - NQ - KQ) * D);
    const float4* frow = (const float4*)fsrc;
    const float4* srow = (const float4*)(sS + lab * 128);
    float dS = 0.f, dd = 0.f;
    #pragma unroll
    for (int i = 0; i < 32; ++i) {
        float4 f = frow[i];
        float4 s = srow[i];
        dS += f.x * s.x + f.y * s.y + f.z * s.z + f.w * s.w;
        // exact replica of the MFMA's diagonal contribution (same cvt ops)
        int wa  = __builtin_amdgcn_cvt_pk_fp8_f32(f.x, f.y, 0, false);
        int wb  = __builtin_amdgcn_cvt_pk_fp8_f32(f.z, f.w, 0, false);
        int wsa = __builtin_amdgcn_cvt_pk_fp8_f32(f.x * SC, f.y * SC, 0, false);
        int wsb = __builtin_amdgcn_cvt_pk_fp8_f32(f.z * SC, f.w * SC, 0, false);
        dd += __builtin_amdgcn_cvt_f32_fp8(wa, 0) * __builtin_amdgcn_cvt_f32_fp8(wsa, 0)
            + __builtin_amdgcn_cvt_f32_fp8(wa, 1) * __builtin_amdgcn_cvt_f32_fp8(wsa, 1)
            + __builtin_amdgcn_cvt_f32_fp8(wb, 0) * __builtin_amdgcn_cvt_f32_fp8(wsb, 0)
            + __builtin_amdgcn_cvt_f32_fp8(wb, 1) * __builtin_amdgcn_cvt_f32_fp8(wsb, 1);
    }
    se -= __builtin_amdgcn_exp2f(dd);
    float lse = logf(se);
    float P = (float)(scnt[lab] - 1);
    float mlpp = (dS - 1.0f) / (TEMPERATURE * P) - lse;
    red[threadIdx.x] = mlpp;
    __syncthreads();
    for (int s2 = 128; s2 > 0; s2 >>= 1) {
        if (threadIdx.x < s2) red[threadIdx.x] += red[threadIdx.x + s2];
        __syncthreads();
    }
    if (threadIdx.x == 0) bsum[blockIdx.x] = red[0];
}

// ---------------------------------------------------------------------------
// K5: final scalar.
// ---------------------------------------------------------------------------
__global__ __launch_bounds__(64) void k_final(const float* __restrict__ bsum,
                                              float* __restrict__ out) {
    float s = bsum[threadIdx.x];                 // RBF=65 > 64, lanes 0..63 valid
    if (threadIdx.x == 0) s += bsum[64];
    #pragma unroll
    for (int m = 1; m < 64; m <<= 1) s += __shfl_xor(s, m);
    if (threadIdx.x == 0) out[0] = -s / (float)N;
}

extern "C" void kernel_launch(void* const* d_in, const int* in_sizes, int n_in,
                              void* d_out, int out_size, void* d_ws, size_t ws_size,
                              hipStream_t stream) {
    const float* q       = (const float*)d_in[0];
    const float* ba      = (const float*)d_in[1];
    const float* nb      = (const float*)d_in[2];
    const long long* tgt = (const long long*)d_in[3];
    char* ws = (char*)d_ws;
    float*         ff   = (float*)(ws + OFF_F32);
    unsigned char* fb8  = (unsigned char*)(ws + OFF_8);
    unsigned char* fb8s = (unsigned char*)(ws + OFF_8S);
    float*         pr   = (float*)(ws + OFF_PR);
    float*         pc   = (float*)(ws + OFF_PC);
    float*         lp   = (float*)(ws + OFF_LP);
    float*         bsum = (float*)(ws + OFF_BSUM);

    k_prep  <<<260,  256, 0, stream>>>(q, ba, nb, tgt, ff, fb8, fb8s, lp);
    k_main  <<<3380, 256, 0, stream>>>(fb8, fb8s, pr, pc);
    k_rowfin<<<RBF,  256, 0, stream>>>(pr, pc, ff, ba, nb, lp, tgt, bsum);
    k_final <<<1,     64, 0, stream>>>(bsum, (float*)d_out);
}

// Round 15
// 82.183 us; speedup vs baseline: 2.0840x; 2.0840x over previous
//
#include <hip/hip_runtime.h>
#include <hip/hip_bf16.h>
#include <stdint.h>

#define TEMPERATURE 0.07f
#define SC 20.6099312f   // log2(e)/T  (SC*ln2 == 1/T; cancellation used in k_rowfin)

constexpr int NQ = 256;
constexpr int KQ = 8192;
constexpr int D  = 128;
constexpr int N  = NQ + 2 * KQ;   // 16640
constexpr int CS = 26;            // column splits (130 tiles / 26 = exactly 5 per block)
constexpr int CS2 = CS * 2;       // part slots (per column-half wave)
constexpr int BN = 128;           // columns per tile
constexpr int RBM = N / 128;      // 130 row blocks for k_main
constexpr int RBF = N / 256;      // 65 blocks for k_rowfin
constexpr int PB = 520;           // k_prep blocks (32 rows each)
constexpr int LB = 16;            // k_lsum blocks

typedef float f32x16 __attribute__((ext_vector_type(16)));
typedef int   i32x4  __attribute__((ext_vector_type(4)));
typedef int   i32x8  __attribute__((ext_vector_type(8)));

// ---- workspace layout (bytes) ----
constexpr size_t OFF_F32  = 0;                                    // float feat [NQ][D] (q rows only)
constexpr size_t OFF_8    = OFF_F32  + (size_t)NQ * D * 4;        // fp8 feat (A side) [N][128]
constexpr size_t OFF_8S   = OFF_8    + (size_t)N * D;             // fp8 feat * SC (B side) [N][128]
constexpr size_t OFF_PART = OFF_8S   + (size_t)N * D;             // partials [CS2][N]
constexpr size_t OFF_LP   = OFF_PART + (size_t)CS2 * N * 4;       // label partials [520][256]
constexpr size_t OFF_LP2  = OFF_LP   + (size_t)PB * 256 * 4;      // stage-2 label partials [16][256]
constexpr size_t OFF_BSUM = OFF_LP2  + (size_t)LB * 256 * 4;      // blocksum [65]

#define MFMA8(a, b, c) __builtin_amdgcn_mfma_scale_f32_32x32x64_f8f6f4( \
    (a), (b), (c), 0, 0, 0, 0x7f7f7f7f, 0, 0x7f7f7f7f)

// ---------------------------------------------------------------------------
// K1: normalize features; emit f32 (q rows only) + two natural-row-major fp8
// copies (unscaled A side, SC-prescaled B side); per-label per-dim partials.
// 520 blocks x 32 rows (4 wave-slices of 8) for latency hiding.
// ---------------------------------------------------------------------------
__global__ __launch_bounds__(256) void k_prep(const float* __restrict__ q,
                                              const float* __restrict__ ba,
                                              const float* __restrict__ nb,
                                              const long long* __restrict__ tgt,
                                              float* __restrict__ ff,
                                              unsigned char* __restrict__ fb8,
                                              unsigned char* __restrict__ fb8s,
                                              float* __restrict__ lp) {
    __shared__ float red[4][2][128];
    int wid = threadIdx.x >> 6, lane = threadIdx.x & 63;
    int rbase = blockIdx.x * 32 + wid * 8;
    float s0x = 0.f, s0y = 0.f, s1x = 0.f, s1y = 0.f;
    #pragma unroll
    for (int i = 0; i < 8; ++i) {
        int r = rbase + i;
        const float* src = (r < NQ) ? (q + (size_t)r * D)
                         : (r < NQ + KQ) ? (ba + (size_t)(r - NQ) * D)
                         : (nb + (size_t)(r - NQ - KQ) * D);
        float2 v = *(const float2*)(src + lane * 2);
        float a = v.x, b = v.y;
        int lab;
        if (r < NQ) {
            float ss = a * a + b * b;
            #pragma unroll
            for (int m = 1; m < 64; m <<= 1) ss += __shfl_xor(ss, m);
            float scale = 1.0f / fmaxf(sqrtf(ss), 1e-12f);
            a *= scale; b *= scale;
            lab = (int)tgt[r];
            *(float2*)(ff + (size_t)r * D + lane * 2) = make_float2(a, b);
        } else {
            lab = (r < NQ + KQ) ? 1 : 0;
        }
        int w8  = __builtin_amdgcn_cvt_pk_fp8_f32(a, b, 0, false);
        int w8s = __builtin_amdgcn_cvt_pk_fp8_f32(a * SC, b * SC, 0, false);
        *(unsigned short*)(fb8  + (size_t)r * D + lane * 2) = (unsigned short)w8;
        *(unsigned short*)(fb8s + (size_t)r * D + lane * 2) = (unsigned short)w8s;
        if (lab) { s1x += a; s1y += b; } else { s0x += a; s0y += b; }
    }
    red[wid][0][lane * 2]     = s0x;
    red[wid][0][lane * 2 + 1] = s0y;
    red[wid][1][lane * 2]     = s1x;
    red[wid][1][lane * 2 + 1] = s1y;
    __syncthreads();
    int lab2 = threadIdx.x >> 7, d = threadIdx.x & 127;
    float s = red[0][lab2][d] + red[1][lab2][d] + red[2][lab2][d] + red[3][lab2][d];
    lp[(size_t)blockIdx.x * 256 + lab2 * 128 + d] = s;
}

// ---------------------------------------------------------------------------
// K2: stage-2 label partial reduce (520 -> 16), parallel over 16 blocks.
// ---------------------------------------------------------------------------
__global__ __launch_bounds__(256) void k_lsum(const float* __restrict__ lp,
                                              float* __restrict__ lp2) {
    int t = threadIdx.x;
    int b0 = blockIdx.x * 33, b1 = min(b0 + 33, PB);
    float s[4] = {0.f, 0.f, 0.f, 0.f};
    for (int b = b0; b < b1; b += 4) {
        #pragma unroll
        for (int j = 0; j < 4; ++j)
            if (b + j < b1) s[j] += lp[(size_t)(b + j) * 256 + t];
    }
    lp2[(size_t)blockIdx.x * 256 + t] = (s[0] + s[1]) + (s[2] + s[3]);
}

// ---------------------------------------------------------------------------
// K3: main fused MX-fp8 GEMM + exp row-sum (proven R12 structure, verbatim).
//   Grid 130*26 = 3380 blocks, 256 threads, 2x2 wave grid, 64x64 per wave.
// ---------------------------------------------------------------------------
__global__ __launch_bounds__(256, 4) void k_main(const unsigned char* __restrict__ fb8,
                                                 const unsigned char* __restrict__ fb8s,
                                                 float* __restrict__ part) {
    __shared__ __align__(16) unsigned char lds[2][BN * 128];   // 2 x 16KB
    const int bid = blockIdx.x;
    const int rb = bid / CS, cs = bid % CS;
    const int tid = threadIdx.x;
    const int lane = tid & 63;
    const int wid  = tid >> 6;                 // 0..3
    const int wr = wid >> 1, wc = wid & 1;     // 2x2 wave grid
    const int l31 = lane & 31, lhi = lane >> 5;
    const int rw = rb * 128 + wr * 64;         // this wave's 64 rows

    // staging: 4 issues x 16B per thread; dest linear, source inverts swizzle.
    int soff[4];
    #pragma unroll
    for (int i = 0; i < 4; ++i) {
        int flat = i * 256 + tid;
        int line = flat >> 4, p = flat & 15;
        int pl = p ^ (line & 15);
        soff[i] = (2 * line + (pl >> 3)) * 128 + (pl & 7) * 16;
    }

#define STAGE(T, B) { \
    const unsigned char* base_ = fb8 + ((size_t)(cs + (T) * CS)) * (BN * 128); \
    _Pragma("unroll") \
    for (int i_ = 0; i_ < 4; ++i_) \
        __builtin_amdgcn_global_load_lds( \
            (const __attribute__((address_space(1))) unsigned int*)(base_ + soff[i_]), \
            (__attribute__((address_space(3))) unsigned int*)(&lds[B][(i_ * 256 + tid) * 16]), \
            16, 0, 0); }

#define SYNC() { asm volatile("s_waitcnt vmcnt(0)" ::: "memory"); __builtin_amdgcn_s_barrier(); }

    // rf: B operand (scaled side), 2 row-groups x 2 K-steps x 32B, loaded once.
    i32x8 rf[2][2];
    #pragma unroll
    for (int rs = 0; rs < 2; ++rs)
        #pragma unroll
        for (int s = 0; s < 2; ++s)
            rf[rs][s] = *(const i32x8*)(fb8s + (size_t)(rw + rs * 32 + l31) * D + s * 64 + lhi * 32);

    f32x16 z16;
    #pragma unroll
    for (int e = 0; e < 16; ++e) z16[e] = 0.f;

    float2 ps2[2] = {{0.f, 0.f}, {0.f, 0.f}};

    STAGE(0, 0) SYNC()

    #pragma unroll 1
    for (int t = 0; t < 5; ++t) {
        if (t + 1 < 5) STAGE(t + 1, (t & 1) ^ 1)
        const unsigned char* buf = &lds[t & 1][0];

        f32x16 acc[2][2];
        __builtin_amdgcn_s_setprio(1);
        #pragma unroll
        for (int s = 0; s < 2; ++s) {
            #pragma unroll
            for (int cc = 0; cc < 2; ++cc) {
                int crow = wc * 64 + cc * 32 + l31;
                int line = crow >> 1;
                int pb = ((crow & 1) << 3) + s * 4 + lhi * 2;
                const unsigned char* lb = buf + line * 256;
                i32x4 lo = *(const i32x4*)(lb + ((pb    ) ^ (line & 15)) * 16);
                i32x4 hi = *(const i32x4*)(lb + ((pb + 1) ^ (line & 15)) * 16);
                i32x8 a = {lo[0], lo[1], lo[2], lo[3], hi[0], hi[1], hi[2], hi[3]};
                acc[cc][0] = MFMA8(a, rf[0][s], (s == 0) ? z16 : acc[cc][0]);
                acc[cc][1] = MFMA8(a, rf[1][s], (s == 0) ? z16 : acc[cc][1]);
            }
        }
        __builtin_amdgcn_s_setprio(0);

        // epilogue: e = exp2(acc) (raw domain), pairwise accumulation.
        #pragma unroll
        for (int cc = 0; cc < 2; ++cc)
            #pragma unroll
            for (int rs = 0; rs < 2; ++rs) {
                float2 p = {0.f, 0.f};
                #pragma unroll
                for (int g = 0; g < 8; ++g) {
                    p.x += __builtin_amdgcn_exp2f(acc[cc][rs][2 * g]);
                    p.y += __builtin_amdgcn_exp2f(acc[cc][rs][2 * g + 1]);
                }
                ps2[rs].x += p.x; ps2[rs].y += p.y;
            }

        SYNC()
    }

    // lane l and l^32 hold the same output row (complementary column subsets).
    float rsum[2] = {ps2[0].x + ps2[0].y, ps2[1].x + ps2[1].y};
    rsum[0] += __shfl_xor(rsum[0], 32);
    rsum[1] += __shfl_xor(rsum[1], 32);
    if (lane < 32) {
        float* dst = part + (size_t)(cs * 2 + wc) * N + rw + lane;
        dst[0]  = rsum[0];
        dst[32] = rsum[1];
    }
#undef STAGE
#undef SYNC
}

// ---------------------------------------------------------------------------
// K4: per-row finalize. Light lp2->S reduce (16 terms) + counts, then
// se = sum(part, 52 slots) - exp2(dd); lse = log(se_raw) (shift cancels).
// ---------------------------------------------------------------------------
__global__ __launch_bounds__(256) void k_rowfin(const float* __restrict__ part,
                                                const float* __restrict__ ff,
                                                const float* __restrict__ ba,
                                                const float* __restrict__ nb,
                                                const float* __restrict__ lp2,
                                                const long long* __restrict__ tgt,
                                                float* __restrict__ bsum) {
    __shared__ float sS[256];
    __shared__ float red[256];
    __shared__ int scnt[2];
    {
        float s[4] = {0.f, 0.f, 0.f, 0.f};
        #pragma unroll
        for (int b = 0; b < LB; b += 4) {
            #pragma unroll
            for (int j = 0; j < 4; ++j)
                s[j] += lp2[(size_t)(b + j) * 256 + threadIdx.x];
        }
        sS[threadIdx.x] = (s[0] + s[1]) + (s[2] + s[3]);
        if (threadIdx.x < 64) {
            int c = 0;
            #pragma unroll
            for (int i = 0; i < 4; ++i) c += (int)tgt[threadIdx.x + 64 * i];
            #pragma unroll
            for (int m = 1; m < 64; m <<= 1) c += __shfl_xor(c, m);
            if (threadIdx.x == 0) { scnt[0] = (NQ - c) + KQ; scnt[1] = c + KQ; }
        }
    }
    __syncthreads();
    int r = blockIdx.x * 256 + threadIdx.x;
    float se = 0.f;
    #pragma unroll 4
    for (int c = 0; c < CS2; ++c) se += part[(size_t)c * N + r];
    int lab = (r < NQ) ? (int)tgt[r] : ((r < NQ + KQ) ? 1 : 0);
    const float* fsrc = (r < NQ) ? (ff + (size_t)r * D)
                      : (r < NQ + KQ) ? (ba + (size_t)(r - NQ) * D)
                      : (nb + (size_t)(r - NQ - KQ) * D);
    const float4* frow = (const float4*)fsrc;
    const float4* srow = (const float4*)(sS + lab * 128);
    float dS = 0.f, dd = 0.f;
    #pragma unroll
    for (int i = 0; i < 32; ++i) {
        float4 f = frow[i];
        float4 s = srow[i];
        dS += f.x * s.x + f.y * s.y + f.z * s.z + f.w * s.w;
        // exact replica of the MFMA's diagonal contribution (same cvt ops)
        int wa  = __builtin_amdgcn_cvt_pk_fp8_f32(f.x, f.y, 0, false);
        int wb  = __builtin_amdgcn_cvt_pk_fp8_f32(f.z, f.w, 0, false);
        int wsa = __builtin_amdgcn_cvt_pk_fp8_f32(f.x * SC, f.y * SC, 0, false);
        int wsb = __builtin_amdgcn_cvt_pk_fp8_f32(f.z * SC, f.w * SC, 0, false);
        dd += __builtin_amdgcn_cvt_f32_fp8(wa, 0) * __builtin_amdgcn_cvt_f32_fp8(wsa, 0)
            + __builtin_amdgcn_cvt_f32_fp8(wa, 1) * __builtin_amdgcn_cvt_f32_fp8(wsa, 1)
            + __builtin_amdgcn_cvt_f32_fp8(wb, 0) * __builtin_amdgcn_cvt_f32_fp8(wsb, 0)
            + __builtin_amdgcn_cvt_f32_fp8(wb, 1) * __builtin_amdgcn_cvt_f32_fp8(wsb, 1);
    }
    se -= __builtin_amdgcn_exp2f(dd);
    float lse = logf(se);
    float P = (float)(scnt[lab] - 1);
    float mlpp = (dS - 1.0f) / (TEMPERATURE * P) - lse;
    red[threadIdx.x] = mlpp;
    __syncthreads();
    for (int s2 = 128; s2 > 0; s2 >>= 1) {
        if (threadIdx.x < s2) red[threadIdx.x] += red[threadIdx.x + s2];
        __syncthreads();
    }
    if (threadIdx.x == 0) bsum[blockIdx.x] = red[0];
}

// ---------------------------------------------------------------------------
// K5: final scalar.
// ---------------------------------------------------------------------------
__global__ __launch_bounds__(64) void k_final(const float* __restrict__ bsum,
                                              float* __restrict__ out) {
    float s = bsum[threadIdx.x];                 // RBF=65 > 64, lanes 0..63 valid
    if (threadIdx.x == 0) s += bsum[64];
    #pragma unroll
    for (int m = 1; m < 64; m <<= 1) s += __shfl_xor(s, m);
    if (threadIdx.x == 0) out[0] = -s / (float)N;
}

extern "C" void kernel_launch(void* const* d_in, const int* in_sizes, int n_in,
                              void* d_out, int out_size, void* d_ws, size_t ws_size,
                              hipStream_t stream) {
    const float* q       = (const float*)d_in[0];
    const float* ba      = (const float*)d_in[1];
    const float* nb      = (const float*)d_in[2];
    const long long* tgt = (const long long*)d_in[3];
    char* ws = (char*)d_ws;
    float*         ff   = (float*)(ws + OFF_F32);
    unsigned char* fb8  = (unsigned char*)(ws + OFF_8);
    unsigned char* fb8s = (unsigned char*)(ws + OFF_8S);
    float*         part = (float*)(ws + OFF_PART);
    float*         lp   = (float*)(ws + OFF_LP);
    float*         lp2  = (float*)(ws + OFF_LP2);
    float*         bsum = (float*)(ws + OFF_BSUM);

    k_prep  <<<PB,       256, 0, stream>>>(q, ba, nb, tgt, ff, fb8, fb8s, lp);
    k_lsum  <<<LB,       256, 0, stream>>>(lp, lp2);
    k_main  <<<RBM * CS, 256, 0, stream>>>(fb8, fb8s, part);
    k_rowfin<<<RBF,      256, 0, stream>>>(part, ff, ba, nb, lp2, tgt, bsum);
    k_final <<<1,         64, 0, stream>>>(bsum, (float*)d_out);
}